// Round 6
// baseline (1288.854 us; speedup 1.0000x reference)
//
#include <hip/hip_runtime.h>
#include <stdint.h>

#define L_ 8
#define D_ 256
#define H_ 8
#define DK_ 32
#define FF_ 1024
#define R_ 37
#define N_ 1024
#define AIB 32   // i-rows per attention block
#define PT_ 40   // probe tiles (5x attn's 8)

// scale * log2(e): attention runs in exp2 domain
#define SCL (0.17677669529663689f * 1.4426950408889634f)

typedef float f4v __attribute__((ext_vector_type(4)));
typedef short b8v __attribute__((ext_vector_type(8)));
typedef uint  u2v __attribute__((ext_vector_type(2)));

__device__ __forceinline__ ushort f2b(float f){
  union { float f; uint32_t u; } x; x.f = f;
  return (ushort)((x.u + 0x7FFFu + ((x.u >> 16) & 1u)) >> 16);
}
__device__ __forceinline__ float b2f(ushort u){
  union { uint32_t u; float f; } x; x.u = ((uint32_t)u) << 16;
  return x.f;
}
__device__ __forceinline__ uint pk2b(float lo, float hi){
  return (((uint)f2b(hi)) << 16) | (uint)f2b(lo);
}
__device__ __forceinline__ float ex2(float x){ return __builtin_amdgcn_exp2f(x); }

__device__ __forceinline__ void lds_fadd(float* p, float v){
  asm volatile("ds_add_f32 %0, %1" :: "v"((uint)(uintptr_t)p), "v"(v) : "memory");
}

// ---------------- weight transpose + cast: src [L][K][Nc] f32 -> dst [L][Nc][K] bf16
__global__ __launch_bounds__(256)
void wcast_kernel(const float* __restrict__ src, ushort* __restrict__ dst, int K, int Nc){
  __shared__ float t[32][33];
  int l = blockIdx.z;
  long base = (long)l * K * Nc;
  int n0 = blockIdx.x * 32, k0 = blockIdx.y * 32;
  int tx = threadIdx.x, ty = threadIdx.y; // (32,8)
  #pragma unroll
  for (int r = 0; r < 32; r += 8)
    t[ty + r][tx] = src[base + (long)(k0 + ty + r) * Nc + n0 + tx];
  __syncthreads();
  #pragma unroll
  for (int r = 0; r < 32; r += 8)
    dst[base + (long)(n0 + ty + r) * K + k0 + tx] = f2b(t[tx][ty + r]);
}

// ---------------- rel int32 -> uint8 (values < 37), once per call
__global__ __launch_bounds__(256)
void rel8_kernel(const int* __restrict__ rel, uint* __restrict__ rel8){
  long idx = (long)blockIdx.x * 256 + threadIdx.x;
  int4 v = ((const int4*)rel)[idx];
  rel8[idx] = (uint)(v.x & 255) | ((uint)(v.y & 255) << 8)
            | ((uint)(v.z & 255) << 16) | ((uint)(v.w & 255) << 24);
}

// ---------------- LayerNorm
template<int OUTB>
__global__ __launch_bounds__(64)
void ln_kernel(const float* __restrict__ x, const float* __restrict__ g, const float* __restrict__ b,
               ushort* __restrict__ ob, float* __restrict__ of){
  int row = blockIdx.x, lane = threadIdx.x;
  float4 v = ((const float4*)(x + (long)row * D_))[lane];
  float s = v.x + v.y + v.z + v.w;
  float s2 = v.x*v.x + v.y*v.y + v.z*v.z + v.w*v.w;
  #pragma unroll
  for (int o = 32; o; o >>= 1){ s += __shfl_xor(s, o); s2 += __shfl_xor(s2, o); }
  float mu = s * (1.f / D_);
  float var = (s2 - D_ * mu * mu) * (1.f / (D_ - 1));
  var = fmaxf(var, 0.f);
  float inv = 1.f / (sqrtf(var) + 1e-6f);
  float4 gv = ((const float4*)g)[lane];
  float4 bv = ((const float4*)b)[lane];
  float o0 = gv.x * (v.x - mu) * inv + bv.x;
  float o1 = gv.y * (v.y - mu) * inv + bv.y;
  float o2 = gv.z * (v.z - mu) * inv + bv.z;
  float o3 = gv.w * (v.w - mu) * inv + bv.w;
  if (OUTB){
    ushort4 u; u.x = f2b(o0); u.y = f2b(o1); u.z = f2b(o2); u.w = f2b(o3);
    ((ushort4*)ob)[(long)row * 64 + lane] = u;
  } else {
    float4 o; o.x = o0; o.y = o1; o.z = o2; o.w = o3;
    ((float4*)of)[(long)row * 64 + lane] = o;
  }
}

// ---------------- bf16 MFMA GEMM. QKV mode: head-split q/k to outB, V^T to outB2.
template<int QKV, int RELU, int RESID, int OUTF, int OUTB>
__global__ __launch_bounds__(256)
void gemm_kernel(const ushort* __restrict__ A,
                 const ushort* __restrict__ W0, const ushort* __restrict__ W1p, const ushort* __restrict__ W2p,
                 const float* __restrict__ B0, const float* __restrict__ B1p, const float* __restrict__ B2p,
                 float* __restrict__ resid, float* __restrict__ outF, ushort* __restrict__ outB,
                 ushort* __restrict__ outB2,
                 int M, int Nc, int K){
  __shared__ ushort Al[64 * 48];
  __shared__ ushort Bl[64 * 48];
  int tid = threadIdx.x;
  int lane = tid & 63, w = tid >> 6;
  int wm = w >> 1, wn = w & 1;
  int bn0 = blockIdx.x * 64, bm0 = blockIdx.y * 64;
  const ushort* WT; const float* bias; int wn0;
  if (QKV){
    int which = bn0 >> 8;
    WT = which == 0 ? W0 : (which == 1 ? W1p : W2p);
    bias = which == 0 ? B0 : (which == 1 ? B1p : B2p);
    wn0 = bn0 & 255;
  } else { WT = W0; bias = B0; wn0 = bn0; }

  int r4 = tid >> 2, c8 = (tid & 3) * 8;
  const ushort* ag = A + (long)(bm0 + r4) * K + c8;
  const ushort* bg = WT + (long)(wn0 + r4) * K + c8;

  f4v acc[2][2];
  #pragma unroll
  for (int i = 0; i < 2; ++i)
    #pragma unroll
    for (int j = 0; j < 2; ++j)
      acc[i][j] = (f4v){0.f, 0.f, 0.f, 0.f};

  int l16 = lane & 15, lg = lane >> 4;
  int arow0 = (wm * 32 + l16) * 48 + lg * 8;
  int brow0 = (wn * 32 + l16) * 48 + lg * 8;

  for (int k0 = 0; k0 < K; k0 += 32){
    b8v a8 = *(const b8v*)(ag + k0);
    b8v b8 = *(const b8v*)(bg + k0);
    __syncthreads();
    *(b8v*)&Al[r4 * 48 + c8] = a8;
    *(b8v*)&Bl[r4 * 48 + c8] = b8;
    __syncthreads();
    b8v a0 = *(const b8v*)&Al[arow0];
    b8v a1 = *(const b8v*)&Al[arow0 + 16 * 48];
    b8v b0 = *(const b8v*)&Bl[brow0];
    b8v b1 = *(const b8v*)&Bl[brow0 + 16 * 48];
    acc[0][0] = __builtin_amdgcn_mfma_f32_16x16x32_bf16(a0, b0, acc[0][0], 0, 0, 0);
    acc[0][1] = __builtin_amdgcn_mfma_f32_16x16x32_bf16(a0, b1, acc[0][1], 0, 0, 0);
    acc[1][0] = __builtin_amdgcn_mfma_f32_16x16x32_bf16(a1, b0, acc[1][0], 0, 0, 0);
    acc[1][1] = __builtin_amdgcn_mfma_f32_16x16x32_bf16(a1, b1, acc[1][1], 0, 0, 0);
  }
  #pragma unroll
  for (int fi = 0; fi < 2; ++fi)
    #pragma unroll
    for (int fj = 0; fj < 2; ++fj){
      int row0 = bm0 + wm * 32 + fi * 16 + lg * 4;
      int col = bn0 + wn * 32 + fj * 16 + l16;
      float vv[4];
      #pragma unroll
      for (int j = 0; j < 4; ++j) vv[j] = acc[fi][fj][j] + bias[QKV ? (col & 255) : col];
      if (QKV){
        int which = col >> 8, hh = (col >> 5) & 7, dk = col & 31;
        if (which == 2){
          ushort4 pk; pk.x = f2b(vv[0]); pk.y = f2b(vv[1]); pk.z = f2b(vv[2]); pk.w = f2b(vv[3]);
          *(ushort4*)(outB2 + (long)hh * 32768 + (long)dk * 1024 + row0) = pk;
        } else {
          #pragma unroll
          for (int j = 0; j < 4; ++j)
            outB[(long)which * 262144 + (long)hh * 32768 + (long)(row0 + j) * 32 + dk] = f2b(vv[j]);
        }
      } else {
        #pragma unroll
        for (int j = 0; j < 4; ++j){
          float v = vv[j];
          if (RELU) v = fmaxf(v, 0.f);
          long idx = (long)(row0 + j) * Nc + col;
          if (RESID) v += resid[idx];
          if (OUTF) outF[idx] = v;
          if (OUTB) outB[idx] = f2b(v);
        }
      }
    }
}

// ---------------- fully-fused MFMA flash attention, now with 1-tile prefetch
__global__ __launch_bounds__(512)
void attn_kernel(const ushort* __restrict__ qb, const ushort* __restrict__ kb,
                 const ushort* __restrict__ vbt, const float* __restrict__ rke,
                 const float* __restrict__ rve,
                 const unsigned char* __restrict__ rel8, ushort* __restrict__ ob){
  __shared__ float q_l[AIB * 32];
  __shared__ float qr_l[AIB * 40];
  __shared__ float prb[4 * AIB * 40];
  __shared__ uint  p_l[8 * 16 * 20];
  __shared__ float part_l[4 * AIB * 34];
  __shared__ float wf_l[4 * AIB];
  __shared__ float lrow_l[AIB];

  int tid = threadIdx.x, lane = tid & 63, w = tid >> 6;
  int l16 = lane & 15, g = lane >> 4;
  int ib0 = blockIdx.x * AIB, h = blockIdx.y;
  int js = w >> 1, ig = w & 1;
  int ir = ig * 16 + l16;

  if (tid < 256){
    int row = tid >> 3, d4 = (tid & 7) * 4;
    ushort4 u = *(const ushort4*)(qb + (long)((h << 10) + ib0 + row) * 32 + d4);
    q_l[row * 32 + d4 + 0] = b2f(u.x);
    q_l[row * 32 + d4 + 1] = b2f(u.y);
    q_l[row * 32 + d4 + 2] = b2f(u.z);
    q_l[row * 32 + d4 + 3] = b2f(u.w);
  }
  for (int idx = tid; idx < 4 * AIB * 40; idx += 512) prb[idx] = 0.f;
  __syncthreads();

  for (int slot = tid; slot < AIB * 40; slot += 512){
    int row = slot / 40, r = slot - row * 40;
    if (r < R_){
      const float* qh = &q_l[row * 32];
      const float* e = rke + r * 32;
      float acc = 0.f;
      #pragma unroll
      for (int d = 0; d < 32; ++d) acc += qh[d] * e[d];
      qr_l[slot] = acc * SCL;
    }
  }
  __syncthreads();

  b8v qf = *(const b8v*)(qb + (long)((h << 10) + ib0 + ir) * 32 + g * 8);

  f4v oacc0 = (f4v){0.f,0.f,0.f,0.f}, oacc1 = (f4v){0.f,0.f,0.f,0.f};
  float m = -3.0e38f, lsum = 0.f;
  const float* qrr = &qr_l[ir * 40];
  float* prr = &prb[(js * AIB + ir) * 40];
  const unsigned char* relrow = rel8 + (long)(ib0 + ir) * N_ + js * 256;
  const ushort* kbh = kb + (long)(h << 10) * 32;
  const ushort* vth = vbt + (long)h * 32 * 1024;
  uint* pw = &p_l[w * 320 + l16 * 20];

  // prologue: tile 0 loads
  int jp = js * 256;
  b8v kf0c = *(const b8v*)(kbh + (long)(jp + l16) * 32 + g * 8);
  b8v kf1c = *(const b8v*)(kbh + (long)(jp + 16 + l16) * 32 + g * 8);
  b8v vt0c = *(const b8v*)(vth + (long)l16 * 1024 + jp + g * 8);
  b8v vt1c = *(const b8v*)(vth + (long)(16 + l16) * 1024 + jp + g * 8);
  uint rr0c = *(const uint*)(relrow + g * 4);
  uint rr1c = *(const uint*)(relrow + 16 + g * 4);

  #pragma unroll
  for (int jt = 0; jt < 8; ++jt){
    // prefetch next tile (wraps to tile 0 on last iter — redundant but harmless)
    int jn = (jt + 1) & 7;
    int j1 = js * 256 + jn * 32;
    b8v kf0n = *(const b8v*)(kbh + (long)(j1 + l16) * 32 + g * 8);
    b8v kf1n = *(const b8v*)(kbh + (long)(j1 + 16 + l16) * 32 + g * 8);
    b8v vt0n = *(const b8v*)(vth + (long)l16 * 1024 + j1 + g * 8);
    b8v vt1n = *(const b8v*)(vth + (long)(16 + l16) * 1024 + j1 + g * 8);
    uint rr0n = *(const uint*)(relrow + jn * 32 + g * 4);
    uint rr1n = *(const uint*)(relrow + jn * 32 + 16 + g * 4);

    f4v z = (f4v){0.f,0.f,0.f,0.f};
    f4v s0 = __builtin_amdgcn_mfma_f32_16x16x32_bf16(kf0c, qf, z, 0, 0, 0);
    f4v s1 = __builtin_amdgcn_mfma_f32_16x16x32_bf16(kf1c, qf, z, 0, 0, 0);

    int rix[8];
    float sv[8];
    #pragma unroll
    for (int e = 0; e < 4; ++e){
      rix[e]     = (rr0c >> (8 * e)) & 255;
      rix[e + 4] = (rr1c >> (8 * e)) & 255;
      sv[e]     = s0[e] * SCL + qrr[rix[e]];
      sv[e + 4] = s1[e] * SCL + qrr[rix[e + 4]];
    }
    float tmax = sv[0];
    #pragma unroll
    for (int e = 1; e < 8; ++e) tmax = fmaxf(tmax, sv[e]);
    tmax = fmaxf(tmax, __shfl_xor(tmax, 16));
    tmax = fmaxf(tmax, __shfl_xor(tmax, 32));

    if (tmax - m > 12.f){
      float f = ex2(m - tmax);
      oacc0 *= f; oacc1 *= f; lsum *= f;
      #pragma unroll
      for (int b2 = 0; b2 < 10; ++b2){
        int bi = g * 10 + b2;
        if (bi < R_) prr[bi] *= f;
      }
      m = tmax;
    }
    float p[8], ps = 0.f;
    #pragma unroll
    for (int e = 0; e < 8; ++e){ p[e] = ex2(sv[e] - m); ps += p[e]; }
    ps += __shfl_xor(ps, 16);
    ps += __shfl_xor(ps, 32);
    lsum += ps;
    #pragma unroll
    for (int e = 0; e < 8; ++e) lds_fadd(&prr[rix[e]], p[e]);

    uint pk0 = pk2b(p[0], p[1]), pk1 = pk2b(p[2], p[3]);
    uint pk2 = pk2b(p[4], p[5]), pk3 = pk2b(p[6], p[7]);
    *(u2v*)&pw[g * 2]     = (u2v){pk0, pk1};
    *(u2v*)&pw[8 + g * 2] = (u2v){pk2, pk3};
    b8v pf = *(const b8v*)&pw[g * 4];
    oacc0 = __builtin_amdgcn_mfma_f32_16x16x32_bf16(vt0c, pf, oacc0, 0, 0, 0);
    oacc1 = __builtin_amdgcn_mfma_f32_16x16x32_bf16(vt1c, pf, oacc1, 0, 0, 0);

    kf0c = kf0n; kf1c = kf1n; vt0c = vt0n; vt1c = vt1n; rr0c = rr0n; rr1c = rr1n;
  }

  {
    float* pp = &part_l[(js * AIB + ir) * 34];
    #pragma unroll
    for (int e = 0; e < 4; ++e){
      pp[g * 4 + e] = oacc0[e];
      pp[16 + g * 4 + e] = oacc1[e];
    }
    if (g == 0){ pp[32] = m; pp[33] = lsum; }
  }
  __syncthreads();

  if (tid < AIB){
    int row = tid;
    float ms[4], ls[4];
    float mstar = -3.0e38f;
    #pragma unroll
    for (int s = 0; s < 4; ++s){
      ms[s] = part_l[(s * AIB + row) * 34 + 32];
      ls[s] = part_l[(s * AIB + row) * 34 + 33];
      mstar = fmaxf(mstar, ms[s]);
    }
    float lstar = 0.f;
    #pragma unroll
    for (int s = 0; s < 4; ++s){
      float wfv = ex2(ms[s] - mstar);
      wf_l[s * AIB + row] = wfv;
      lstar += ls[s] * wfv;
    }
    lrow_l[row] = lstar;
  }
  __syncthreads();

  for (int slot = tid; slot < AIB * 40; slot += 512){
    int row = slot / 40;
    float acc = 0.f;
    #pragma unroll
    for (int s = 0; s < 4; ++s) acc += prb[(s * AIB) * 40 + slot] * wf_l[s * AIB + row];
    prb[slot] = acc;
  }
  __syncthreads();

  for (int slot = tid; slot < AIB * 32; slot += 512){
    int row = slot >> 5, d = slot & 31;
    float o1 = 0.f;
    #pragma unroll
    for (int s = 0; s < 4; ++s) o1 += part_l[(s * AIB + row) * 34 + d] * wf_l[s * AIB + row];
    float o2 = 0.f;
    #pragma unroll
    for (int r = 0; r < R_; ++r) o2 += prb[row * 40 + r] * rve[r * 32 + d];
    float val = (o1 + o2) / lrow_l[row];
    ob[(long)(ib0 + row) * D_ + h * 32 + d] = f2b(val);
  }
}

// ---------------- DIAGNOSTIC PROBES (read-only; results sunk via asm; no output writes)
// MODE 0: per-tile global loads + MFMAs, NO softmax/gather/repack chain
// MODE 1: full softmax/gather/repack chain + MFMAs, NO per-tile global loads
// MODE 2: full inner-loop body (loads + chain)
template<int MODE>
__global__ __launch_bounds__(512)
void probe_kernel(const ushort* __restrict__ qb, const ushort* __restrict__ kb,
                  const ushort* __restrict__ vbt, const unsigned char* __restrict__ rel8,
                  const float* __restrict__ rke){
  __shared__ float qr_l[AIB * 40];
  __shared__ float prb[4 * AIB * 40];
  __shared__ uint  p_l[8 * 16 * 20];

  int tid = threadIdx.x, lane = tid & 63, w = tid >> 6;
  int l16 = lane & 15, g = lane >> 4;
  int ib0 = blockIdx.x * AIB, h = blockIdx.y;
  int js = w >> 1, ig = w & 1;
  int ir = ig * 16 + l16;

  for (int idx = tid; idx < AIB * 40; idx += 512) qr_l[idx] = rke[idx & 1023];
  for (int idx = tid; idx < 4 * AIB * 40; idx += 512) prb[idx] = 0.f;
  __syncthreads();

  b8v qf = *(const b8v*)(qb + (long)((h << 10) + ib0 + ir) * 32 + g * 8);
  f4v oacc0 = (f4v){0.f,0.f,0.f,0.f}, oacc1 = (f4v){0.f,0.f,0.f,0.f};
  float m = 0.f, lsum = 0.f;
  const float* qrr = &qr_l[ir * 40];
  float* prr = &prb[(js * AIB + ir) * 40];
  const unsigned char* relrow = rel8 + (long)(ib0 + ir) * N_ + js * 256;
  const ushort* kbh = kb + (long)(h << 10) * 32;
  const ushort* vth = vbt + (long)h * 32 * 1024;
  uint* pw = &p_l[w * 320 + l16 * 20];

  b8v kf0 = *(const b8v*)(kbh + (long)l16 * 32 + g * 8);
  b8v kf1 = *(const b8v*)(kbh + (long)(16 + l16) * 32 + g * 8);
  b8v vt0 = *(const b8v*)(vth + (long)l16 * 1024 + g * 8);
  b8v vt1 = *(const b8v*)(vth + (long)(16 + l16) * 1024 + g * 8);
  uint rr0 = *(const uint*)(relrow + g * 4);
  uint rr1 = *(const uint*)(relrow + 16 + g * 4);

  for (int jt = 0; jt < PT_; ++jt){
    int j0 = js * 256 + (jt & 7) * 32;
    if (MODE != 1){
      kf0 = *(const b8v*)(kbh + (long)(j0 + l16) * 32 + g * 8);
      kf1 = *(const b8v*)(kbh + (long)(j0 + 16 + l16) * 32 + g * 8);
      vt0 = *(const b8v*)(vth + (long)l16 * 1024 + j0 + g * 8);
      vt1 = *(const b8v*)(vth + (long)(16 + l16) * 1024 + j0 + g * 8);
      rr0 = *(const uint*)(relrow + (jt & 7) * 32 + g * 4);
      rr1 = *(const uint*)(relrow + (jt & 7) * 32 + 16 + g * 4);
    }
    f4v z = (f4v){0.f,0.f,0.f,0.f};
    f4v s0 = __builtin_amdgcn_mfma_f32_16x16x32_bf16(kf0, qf, z, 0, 0, 0);
    f4v s1 = __builtin_amdgcn_mfma_f32_16x16x32_bf16(kf1, qf, z, 0, 0, 0);

    if (MODE == 0){
      // keep rel loads + S-MFMAs live, skip the chain
      union { uint u[4]; b8v v; } pu;
      pu.u[0] = rr0; pu.u[1] = rr1; pu.u[2] = rr0 ^ (uint)jt; pu.u[3] = rr1 + 1u;
      b8v pf = pu.v;
      oacc0 = __builtin_amdgcn_mfma_f32_16x16x32_bf16(vt0, pf, oacc0, 0, 0, 0);
      oacc1 = __builtin_amdgcn_mfma_f32_16x16x32_bf16(vt1, pf, oacc1, 0, 0, 0);
      oacc0 += s0; oacc1 += s1;
    } else {
      int rix[8];
      float sv[8];
      #pragma unroll
      for (int e = 0; e < 4; ++e){
        rix[e]     = (int)((rr0 >> (8 * e)) + (uint)jt) & 31;
        rix[e + 4] = (int)((rr1 >> (8 * e)) + (uint)jt) & 31;
        sv[e]     = s0[e] * SCL + qrr[rix[e]];
        sv[e + 4] = s1[e] * SCL + qrr[rix[e + 4]];
      }
      float tmax = sv[0];
      #pragma unroll
      for (int e = 1; e < 8; ++e) tmax = fmaxf(tmax, sv[e]);
      tmax = fmaxf(tmax, __shfl_xor(tmax, 16));
      tmax = fmaxf(tmax, __shfl_xor(tmax, 32));
      if (tmax - m > 12.f){
        float f = ex2(m - tmax);
        oacc0 *= f; oacc1 *= f; lsum *= f;
        #pragma unroll
        for (int b2 = 0; b2 < 10; ++b2){
          int bi = g * 10 + b2;
          if (bi < R_) prr[bi] *= f;
        }
        m = tmax;
      }
      float p[8], ps = 0.f;
      #pragma unroll
      for (int e = 0; e < 8; ++e){ p[e] = ex2(sv[e] - m); ps += p[e]; }
      ps += __shfl_xor(ps, 16);
      ps += __shfl_xor(ps, 32);
      lsum += ps;
      #pragma unroll
      for (int e = 0; e < 8; ++e) lds_fadd(&prr[rix[e]], p[e]);

      uint pk0 = pk2b(p[0], p[1]), pk1 = pk2b(p[2], p[3]);
      uint pk2 = pk2b(p[4], p[5]), pk3 = pk2b(p[6], p[7]);
      *(u2v*)&pw[g * 2]     = (u2v){pk0, pk1};
      *(u2v*)&pw[8 + g * 2] = (u2v){pk2, pk3};
      b8v pf = *(const b8v*)&pw[g * 4];
      oacc0 = __builtin_amdgcn_mfma_f32_16x16x32_bf16(vt0, pf, oacc0, 0, 0, 0);
      oacc1 = __builtin_amdgcn_mfma_f32_16x16x32_bf16(vt1, pf, oacc1, 0, 0, 0);
      if (MODE == 1){
        // loop-carried feedback so per-tile MFMAs can't be hoisted (no loads in this mode)
        kf0 = pf;
        kf1 ^= pf;
      }
    }
  }
  asm volatile("" :: "v"(oacc0[0]), "v"(oacc0[1]), "v"(oacc1[0]), "v"(oacc1[1]),
                     "v"(m), "v"(lsum));
}

extern "C" void kernel_launch(void* const* d_in, const int* in_sizes, int n_in,
                              void* d_out, int out_size, void* d_ws, size_t ws_size,
                              hipStream_t stream){
  const float* x    = (const float*)d_in[0];
  const int*   rel  = (const int*)d_in[1];
  const float* Wq   = (const float*)d_in[2];
  const float* bq   = (const float*)d_in[3];
  const float* Wk   = (const float*)d_in[4];
  const float* bk   = (const float*)d_in[5];
  const float* Wv   = (const float*)d_in[6];
  const float* bv   = (const float*)d_in[7];
  const float* Wo   = (const float*)d_in[8];
  const float* bo   = (const float*)d_in[9];
  const float* rke  = (const float*)d_in[10];
  const float* rve  = (const float*)d_in[11];
  const float* W1   = (const float*)d_in[12];
  const float* b1   = (const float*)d_in[13];
  const float* W2   = (const float*)d_in[14];
  const float* b2   = (const float*)d_in[15];
  const float* ln1g = (const float*)d_in[16];
  const float* ln1b = (const float*)d_in[17];
  const float* ln2g = (const float*)d_in[18];
  const float* ln2b = (const float*)d_in[19];
  const float* lnfg = (const float*)d_in[20];
  const float* lnfb = (const float*)d_in[21];

  char* wsb = (char*)d_ws;
  size_t off = 0;
  auto alloc = [&](size_t bytes){ void* p = wsb + off; off += (bytes + 255) & ~255ull; return p; };
  float*  xw   = (float*) alloc((size_t)N_ * D_ * 4);
  ushort* qkvb = (ushort*)alloc((size_t)3 * H_ * N_ * DK_ * 2);
  ushort* vbt  = (ushort*)alloc((size_t)H_ * DK_ * N_ * 2);
  ushort* xnb  = (ushort*)alloc((size_t)N_ * D_ * 2);
  ushort* obf  = (ushort*)alloc((size_t)N_ * D_ * 2);
  ushort* hidb = (ushort*)alloc((size_t)N_ * FF_ * 2);
  uint*   rel8 = (uint*)  alloc((size_t)N_ * N_);
  ushort* wqT  = (ushort*)alloc((size_t)L_ * D_ * D_ * 2);
  ushort* wkT  = (ushort*)alloc((size_t)L_ * D_ * D_ * 2);
  ushort* wvT  = (ushort*)alloc((size_t)L_ * D_ * D_ * 2);
  ushort* woT  = (ushort*)alloc((size_t)L_ * D_ * D_ * 2);
  ushort* w1T  = (ushort*)alloc((size_t)L_ * D_ * FF_ * 2);
  ushort* w2T  = (ushort*)alloc((size_t)L_ * D_ * FF_ * 2);
  (void)ws_size; (void)in_sizes; (void)n_in; (void)out_size;

  ushort* qb = qkvb;
  ushort* kb = qkvb + (size_t)H_ * N_ * DK_;

  dim3 tb(32, 8);
  wcast_kernel<<<dim3(D_/32,  D_/32,  L_), tb, 0, stream>>>(Wq, wqT, D_, D_);
  wcast_kernel<<<dim3(D_/32,  D_/32,  L_), tb, 0, stream>>>(Wk, wkT, D_, D_);
  wcast_kernel<<<dim3(D_/32,  D_/32,  L_), tb, 0, stream>>>(Wv, wvT, D_, D_);
  wcast_kernel<<<dim3(D_/32,  D_/32,  L_), tb, 0, stream>>>(Wo, woT, D_, D_);
  wcast_kernel<<<dim3(FF_/32, D_/32,  L_), tb, 0, stream>>>(W1, w1T, D_, FF_);
  wcast_kernel<<<dim3(D_/32,  FF_/32, L_), tb, 0, stream>>>(W2, w2T, FF_, D_);
  rel8_kernel<<<N_ * N_ / 1024, 256, 0, stream>>>(rel, rel8);

  hipMemcpyAsync(xw, x, (size_t)N_ * D_ * 4, hipMemcpyDeviceToDevice, stream);

  for (int l = 0; l < L_; ++l){
    ln_kernel<1><<<N_, 64, 0, stream>>>(xw, ln1g + l * D_, ln1b + l * D_, xnb, nullptr);
    gemm_kernel<1,0,0,0,1><<<dim3(768/64, N_/64), 256, 0, stream>>>(
        xnb, wqT + (size_t)l * D_ * D_, wkT + (size_t)l * D_ * D_, wvT + (size_t)l * D_ * D_,
        bq + l * D_, bk + l * D_, bv + l * D_,
        nullptr, nullptr, qkvb, vbt, N_, 768, D_);
    attn_kernel<<<dim3(N_/AIB, H_), 512, 0, stream>>>(
        qb, kb, vbt, rke + (size_t)l * R_ * DK_, rve + (size_t)l * R_ * DK_,
        (const unsigned char*)rel8, obf);
    gemm_kernel<0,0,1,1,0><<<dim3(D_/64, N_/64), 256, 0, stream>>>(
        obf, woT + (size_t)l * D_ * D_, nullptr, nullptr,
        bo + l * D_, nullptr, nullptr,
        xw, xw, nullptr, nullptr, N_, D_, D_);
    ln_kernel<1><<<N_, 64, 0, stream>>>(xw, ln2g + l * D_, ln2b + l * D_, xnb, nullptr);
    gemm_kernel<0,1,0,0,1><<<dim3(FF_/64, N_/64), 256, 0, stream>>>(
        xnb, w1T + (size_t)l * D_ * FF_, nullptr, nullptr,
        b1 + l * FF_, nullptr, nullptr,
        nullptr, nullptr, hidb, nullptr, N_, FF_, D_);
    gemm_kernel<0,0,1,1,0><<<dim3(D_/64, N_/64), 256, 0, stream>>>(
        hidb, w2T + (size_t)l * FF_ * D_, nullptr, nullptr,
        b2 + l * D_, nullptr, nullptr,
        xw, xw, nullptr, nullptr, N_, D_, FF_);
  }
  ln_kernel<0><<<N_, 64, 0, stream>>>(xw, lnfg, lnfb, nullptr, (float*)d_out);

  // diagnostic probes (read-only, no visible writes)
  probe_kernel<0><<<dim3(N_/AIB, H_), 512, 0, stream>>>(qb, kb, vbt, (const unsigned char*)rel8, rke);
  probe_kernel<1><<<dim3(N_/AIB, H_), 512, 0, stream>>>(qb, kb, vbt, (const unsigned char*)rel8, rke);
  probe_kernel<2><<<dim3(N_/AIB, H_), 512, 0, stream>>>(qb, kb, vbt, (const unsigned char*)rel8, rke);
}

// Round 7
// 787.422 us; speedup vs baseline: 1.6368x; 1.6368x over previous
//
#include <hip/hip_runtime.h>
#include <stdint.h>

#define L_ 8
#define D_ 256
#define H_ 8
#define DK_ 32
#define FF_ 1024
#define R_ 37
#define N_ 1024
#define AIB 16   // i-rows per attention block (8-way j-split inside block)

// scale * log2(e): attention runs in exp2 domain
#define SCL (0.17677669529663689f * 1.4426950408889634f)

typedef float f4v __attribute__((ext_vector_type(4)));
typedef short b8v __attribute__((ext_vector_type(8)));
typedef uint  u2v __attribute__((ext_vector_type(2)));

__device__ __forceinline__ ushort f2b(float f){
  union { float f; uint32_t u; } x; x.f = f;
  return (ushort)((x.u + 0x7FFFu + ((x.u >> 16) & 1u)) >> 16);
}
__device__ __forceinline__ float b2f(ushort u){
  union { uint32_t u; float f; } x; x.u = ((uint32_t)u) << 16;
  return x.f;
}
__device__ __forceinline__ uint pk2b(float lo, float hi){
  return (((uint)f2b(hi)) << 16) | (uint)f2b(lo);
}
__device__ __forceinline__ float ex2(float x){ return __builtin_amdgcn_exp2f(x); }

// native LDS float add (fire-and-forget, no CAS loop)
__device__ __forceinline__ void lds_fadd(float* p, float v){
  asm volatile("ds_add_f32 %0, %1" :: "v"((uint)(uintptr_t)p), "v"(v) : "memory");
}

// ---------------- weight transpose + cast: src [L][K][Nc] f32 -> dst [L][Nc][K] bf16
__global__ __launch_bounds__(256)
void wcast_kernel(const float* __restrict__ src, ushort* __restrict__ dst, int K, int Nc){
  __shared__ float t[32][33];
  int l = blockIdx.z;
  long base = (long)l * K * Nc;
  int n0 = blockIdx.x * 32, k0 = blockIdx.y * 32;
  int tx = threadIdx.x, ty = threadIdx.y; // (32,8)
  #pragma unroll
  for (int r = 0; r < 32; r += 8)
    t[ty + r][tx] = src[base + (long)(k0 + ty + r) * Nc + n0 + tx];
  __syncthreads();
  #pragma unroll
  for (int r = 0; r < 32; r += 8)
    dst[base + (long)(n0 + ty + r) * K + k0 + tx] = f2b(t[tx][ty + r]);
}

// ---------------- rel int32 -> uint8 (values < 37), once per call
__global__ __launch_bounds__(256)
void rel8_kernel(const int* __restrict__ rel, uint* __restrict__ rel8){
  long idx = (long)blockIdx.x * 256 + threadIdx.x;
  int4 v = ((const int4*)rel)[idx];
  rel8[idx] = (uint)(v.x & 255) | ((uint)(v.y & 255) << 8)
            | ((uint)(v.z & 255) << 16) | ((uint)(v.w & 255) << 24);
}

// ---------------- LayerNorm
template<int OUTB>
__global__ __launch_bounds__(64)
void ln_kernel(const float* __restrict__ x, const float* __restrict__ g, const float* __restrict__ b,
               ushort* __restrict__ ob, float* __restrict__ of){
  int row = blockIdx.x, lane = threadIdx.x;
  float4 v = ((const float4*)(x + (long)row * D_))[lane];
  float s = v.x + v.y + v.z + v.w;
  float s2 = v.x*v.x + v.y*v.y + v.z*v.z + v.w*v.w;
  #pragma unroll
  for (int o = 32; o; o >>= 1){ s += __shfl_xor(s, o); s2 += __shfl_xor(s2, o); }
  float mu = s * (1.f / D_);
  float var = (s2 - D_ * mu * mu) * (1.f / (D_ - 1));
  var = fmaxf(var, 0.f);
  float inv = 1.f / (sqrtf(var) + 1e-6f);
  float4 gv = ((const float4*)g)[lane];
  float4 bv = ((const float4*)b)[lane];
  float o0 = gv.x * (v.x - mu) * inv + bv.x;
  float o1 = gv.y * (v.y - mu) * inv + bv.y;
  float o2 = gv.z * (v.z - mu) * inv + bv.z;
  float o3 = gv.w * (v.w - mu) * inv + bv.w;
  if (OUTB){
    ushort4 u; u.x = f2b(o0); u.y = f2b(o1); u.z = f2b(o2); u.w = f2b(o3);
    ((ushort4*)ob)[(long)row * 64 + lane] = u;
  } else {
    float4 o; o.x = o0; o.y = o1; o.z = o2; o.w = o3;
    ((float4*)of)[(long)row * 64 + lane] = o;
  }
}

// ---------------- bf16 MFMA GEMM. QKV mode: head-split q/k to outB, V^T to outB2.
template<int QKV, int RELU, int RESID, int OUTF, int OUTB>
__global__ __launch_bounds__(256)
void gemm_kernel(const ushort* __restrict__ A,
                 const ushort* __restrict__ W0, const ushort* __restrict__ W1p, const ushort* __restrict__ W2p,
                 const float* __restrict__ B0, const float* __restrict__ B1p, const float* __restrict__ B2p,
                 float* __restrict__ resid, float* __restrict__ outF, ushort* __restrict__ outB,
                 ushort* __restrict__ outB2,
                 int M, int Nc, int K){
  __shared__ ushort Al[64 * 48];
  __shared__ ushort Bl[64 * 48];
  int tid = threadIdx.x;
  int lane = tid & 63, w = tid >> 6;
  int wm = w >> 1, wn = w & 1;
  int bn0 = blockIdx.x * 64, bm0 = blockIdx.y * 64;
  const ushort* WT; const float* bias; int wn0;
  if (QKV){
    int which = bn0 >> 8;
    WT = which == 0 ? W0 : (which == 1 ? W1p : W2p);
    bias = which == 0 ? B0 : (which == 1 ? B1p : B2p);
    wn0 = bn0 & 255;
  } else { WT = W0; bias = B0; wn0 = bn0; }

  int r4 = tid >> 2, c8 = (tid & 3) * 8;
  const ushort* ag = A + (long)(bm0 + r4) * K + c8;
  const ushort* bg = WT + (long)(wn0 + r4) * K + c8;

  f4v acc[2][2];
  #pragma unroll
  for (int i = 0; i < 2; ++i)
    #pragma unroll
    for (int j = 0; j < 2; ++j)
      acc[i][j] = (f4v){0.f, 0.f, 0.f, 0.f};

  int l16 = lane & 15, lg = lane >> 4;
  int arow0 = (wm * 32 + l16) * 48 + lg * 8;
  int brow0 = (wn * 32 + l16) * 48 + lg * 8;

  for (int k0 = 0; k0 < K; k0 += 32){
    b8v a8 = *(const b8v*)(ag + k0);
    b8v b8 = *(const b8v*)(bg + k0);
    __syncthreads();
    *(b8v*)&Al[r4 * 48 + c8] = a8;
    *(b8v*)&Bl[r4 * 48 + c8] = b8;
    __syncthreads();
    b8v a0 = *(const b8v*)&Al[arow0];
    b8v a1 = *(const b8v*)&Al[arow0 + 16 * 48];
    b8v b0 = *(const b8v*)&Bl[brow0];
    b8v b1 = *(const b8v*)&Bl[brow0 + 16 * 48];
    acc[0][0] = __builtin_amdgcn_mfma_f32_16x16x32_bf16(a0, b0, acc[0][0], 0, 0, 0);
    acc[0][1] = __builtin_amdgcn_mfma_f32_16x16x32_bf16(a0, b1, acc[0][1], 0, 0, 0);
    acc[1][0] = __builtin_amdgcn_mfma_f32_16x16x32_bf16(a1, b0, acc[1][0], 0, 0, 0);
    acc[1][1] = __builtin_amdgcn_mfma_f32_16x16x32_bf16(a1, b1, acc[1][1], 0, 0, 0);
  }
  #pragma unroll
  for (int fi = 0; fi < 2; ++fi)
    #pragma unroll
    for (int fj = 0; fj < 2; ++fj){
      int row0 = bm0 + wm * 32 + fi * 16 + lg * 4;
      int col = bn0 + wn * 32 + fj * 16 + l16;
      float vv[4];
      #pragma unroll
      for (int j = 0; j < 4; ++j) vv[j] = acc[fi][fj][j] + bias[QKV ? (col & 255) : col];
      if (QKV){
        int which = col >> 8, hh = (col >> 5) & 7, dk = col & 31;
        if (which == 2){
          ushort4 pk; pk.x = f2b(vv[0]); pk.y = f2b(vv[1]); pk.z = f2b(vv[2]); pk.w = f2b(vv[3]);
          *(ushort4*)(outB2 + (long)hh * 32768 + (long)dk * 1024 + row0) = pk;
        } else {
          #pragma unroll
          for (int j = 0; j < 4; ++j)
            outB[(long)which * 262144 + (long)hh * 32768 + (long)(row0 + j) * 32 + dk] = f2b(vv[j]);
        }
      } else {
        #pragma unroll
        for (int j = 0; j < 4; ++j){
          float v = vv[j];
          if (RELU) v = fmaxf(v, 0.f);
          long idx = (long)(row0 + j) * Nc + col;
          if (RESID) v += resid[idx];
          if (OUTF) outF[idx] = v;
          if (OUTB) outB[idx] = f2b(v);
        }
      }
    }
}

// ---------------- fused MFMA flash attention v2: all gathers hoisted, minimal chain
// grid (N/16, H), 512 threads = 8 waves; wave w = j-split slice of 128 j (4 tiles of 32)
__global__ __launch_bounds__(512)
void attn_kernel(const ushort* __restrict__ qb, const ushort* __restrict__ kb,
                 const ushort* __restrict__ vbt, const float* __restrict__ rke,
                 const float* __restrict__ rve,
                 const unsigned char* __restrict__ rel8, ushort* __restrict__ ob){
  __shared__ float q_l[AIB * 32];        // 2KB   f32 q rows
  __shared__ float qr_l[AIB * 40];       // 2.5KB per-row relation bias table
  __shared__ float prb[8 * AIB * 41];    // 21KB  relation bins per (js,row), stride 41 (bank-bijective)
  __shared__ uint  p_l[8 * AIB * 20];    // 10KB  P^T repack, wave-private
  __shared__ float part_l[8 * AIB * 33]; // 17KB  per (js,row): o[32], m
  __shared__ float wf_l[8 * AIB];
  __shared__ float ls_l[8 * AIB];
  __shared__ float lrow_l[AIB];

  int tid = threadIdx.x, lane = tid & 63, w = tid >> 6;
  int l16 = lane & 15, g = lane >> 4;
  int ib0 = blockIdx.x * AIB, h = blockIdx.y;
  int ir = l16;

  // stage q (f32)
  if (tid < 128){
    int row = tid >> 3, d4 = (tid & 7) * 4;
    ushort4 u = *(const ushort4*)(qb + (long)((h << 10) + ib0 + row) * 32 + d4);
    q_l[row * 32 + d4 + 0] = b2f(u.x);
    q_l[row * 32 + d4 + 1] = b2f(u.y);
    q_l[row * 32 + d4 + 2] = b2f(u.z);
    q_l[row * 32 + d4 + 3] = b2f(u.w);
  }
  for (int idx = tid; idx < 8 * AIB * 41; idx += 512) prb[idx] = 0.f;
  __syncthreads();

  // qr[row][r] = SCL * q[row,:] . rke[r,:]
  for (int slot = tid; slot < AIB * 40; slot += 512){
    int row = slot / 40, r = slot - row * 40;
    if (r < R_){
      const float* qh = &q_l[row * 32];
      const float* e = rke + r * 32;
      float acc = 0.f;
      #pragma unroll
      for (int d = 0; d < 32; ++d) acc += qh[d] * e[d];
      qr_l[slot] = acc * SCL;
    }
  }
  __syncthreads();

  b8v qf = *(const b8v*)(qb + (long)((h << 10) + ib0 + ir) * 32 + g * 8);

  f4v oacc0 = (f4v){0.f,0.f,0.f,0.f}, oacc1 = (f4v){0.f,0.f,0.f,0.f};
  float m = -3.0e38f;
  const float* qrr = &qr_l[ir * 40];
  float* prr = &prb[(w * AIB + ir) * 41];
  const unsigned char* relrow = rel8 + (long)(ib0 + ir) * N_ + w * 128;
  const ushort* kbh = kb + (long)(h << 10) * 32;
  const ushort* vth = vbt + (long)h * 32 * 1024;
  uint* pw = &p_l[(w * AIB + l16) * 20];

  // hoist ALL rel dwords (8) and ALL bias gathers (32) out of the loop
  uint raw[8];
  #pragma unroll
  for (int t = 0; t < 4; ++t){
    raw[t * 2]     = *(const uint*)(relrow + t * 32 + g * 4);
    raw[t * 2 + 1] = *(const uint*)(relrow + t * 32 + 16 + g * 4);
  }
  float qv[32];
  #pragma unroll
  for (int t = 0; t < 4; ++t)
    #pragma unroll
    for (int e = 0; e < 4; ++e){
      qv[t * 8 + e]     = qrr[(raw[t * 2]     >> (8 * e)) & 255];
      qv[t * 8 + 4 + e] = qrr[(raw[t * 2 + 1] >> (8 * e)) & 255];
    }

  // K/V register prefetch, 1 tile ahead
  int jb = w * 128;
  b8v kf0c = *(const b8v*)(kbh + (long)(jb + l16) * 32 + g * 8);
  b8v kf1c = *(const b8v*)(kbh + (long)(jb + 16 + l16) * 32 + g * 8);
  b8v vt0c = *(const b8v*)(vth + (long)l16 * 1024 + jb + g * 8);
  b8v vt1c = *(const b8v*)(vth + (long)(16 + l16) * 1024 + jb + g * 8);

  #pragma unroll
  for (int t = 0; t < 4; ++t){
    int j1 = jb + ((t + 1) & 3) * 32;
    b8v kf0n = *(const b8v*)(kbh + (long)(j1 + l16) * 32 + g * 8);
    b8v kf1n = *(const b8v*)(kbh + (long)(j1 + 16 + l16) * 32 + g * 8);
    b8v vt0n = *(const b8v*)(vth + (long)l16 * 1024 + j1 + g * 8);
    b8v vt1n = *(const b8v*)(vth + (long)(16 + l16) * 1024 + j1 + g * 8);

    f4v z = (f4v){0.f,0.f,0.f,0.f};
    f4v s0 = __builtin_amdgcn_mfma_f32_16x16x32_bf16(kf0c, qf, z, 0, 0, 0);
    f4v s1 = __builtin_amdgcn_mfma_f32_16x16x32_bf16(kf1c, qf, z, 0, 0, 0);

    float sv[8];
    #pragma unroll
    for (int e = 0; e < 4; ++e){
      sv[e]     = s0[e] * SCL + qv[t * 8 + e];
      sv[e + 4] = s1[e] * SCL + qv[t * 8 + 4 + e];
    }
    float lmax = sv[0];
    #pragma unroll
    for (int e = 1; e < 8; ++e) lmax = fmaxf(lmax, sv[e]);

    // defer-max: full reduce + rescale only if some lane exceeds headroom (rare)
    if (__any(lmax - m > 12.f)){
      float tmax = fmaxf(lmax, __shfl_xor(lmax, 16));
      tmax = fmaxf(tmax, __shfl_xor(tmax, 32));
      if (tmax > m){
        float f = ex2(m - tmax);
        oacc0 *= f; oacc1 *= f;
        #pragma unroll
        for (int b2 = 0; b2 < 10; ++b2){
          int bi = g * 10 + b2;
          if (bi < R_) prr[bi] *= f;
        }
        m = tmax;
      }
    }
    float p[8];
    #pragma unroll
    for (int e = 0; e < 8; ++e) p[e] = ex2(sv[e] - m);
    #pragma unroll
    for (int e = 0; e < 4; ++e){
      lds_fadd(&prr[(raw[t * 2]     >> (8 * e)) & 255], p[e]);
      lds_fadd(&prr[(raw[t * 2 + 1] >> (8 * e)) & 255], p[e + 4]);
    }

    // repack P^T to bf16 B-fragment via wave-private LDS (no barrier)
    uint pk0 = pk2b(p[0], p[1]), pk1 = pk2b(p[2], p[3]);
    uint pk2 = pk2b(p[4], p[5]), pk3 = pk2b(p[6], p[7]);
    *(u2v*)&pw[g * 2]     = (u2v){pk0, pk1};
    *(u2v*)&pw[8 + g * 2] = (u2v){pk2, pk3};
    b8v pf = *(const b8v*)&pw[g * 4];
    oacc0 = __builtin_amdgcn_mfma_f32_16x16x32_bf16(vt0c, pf, oacc0, 0, 0, 0);
    oacc1 = __builtin_amdgcn_mfma_f32_16x16x32_bf16(vt1c, pf, oacc1, 0, 0, 0);

    kf0c = kf0n; kf1c = kf1n; vt0c = vt0n; vt1c = vt1n;
  }

  // write per-wave partial (o + m); lsum recovered from bins at combine
  {
    float* pp = &part_l[(w * AIB + ir) * 33];
    #pragma unroll
    for (int e = 0; e < 4; ++e){
      pp[g * 4 + e] = oacc0[e];
      pp[16 + g * 4 + e] = oacc1[e];
    }
    if (g == 0) pp[32] = m;
  }
  __syncthreads();

  // per-(js,row) l = sum of bins
  for (int slot = tid; slot < 8 * AIB; slot += 512){
    const float* pb = &prb[slot * 41];
    float acc = 0.f;
    #pragma unroll
    for (int r = 0; r < R_; ++r) acc += pb[r];
    ls_l[slot] = acc;
  }
  __syncthreads();

  // per-row combine weights
  if (tid < AIB){
    int row = tid;
    float mstar = -3.0e38f;
    #pragma unroll
    for (int s = 0; s < 8; ++s) mstar = fmaxf(mstar, part_l[(s * AIB + row) * 33 + 32]);
    float lstar = 0.f;
    #pragma unroll
    for (int s = 0; s < 8; ++s){
      float wfv = ex2(part_l[(s * AIB + row) * 33 + 32] - mstar);
      wf_l[s * AIB + row] = wfv;
      lstar += ls_l[s * AIB + row] * wfv;
    }
    lrow_l[row] = lstar;
  }
  __syncthreads();

  // merge bins across j-splits (into s=0 region)
  for (int slot = tid; slot < AIB * 41; slot += 512){
    int row = slot / 41;
    float acc = 0.f;
    #pragma unroll
    for (int s = 0; s < 8; ++s) acc += prb[s * AIB * 41 + slot] * wf_l[s * AIB + row];
    prb[slot] = acc;
  }
  __syncthreads();

  // final output: o = (sum_s wf*o_s + bins @ rve) / lstar
  {
    int row = tid >> 5, d = tid & 31;
    float o1 = 0.f;
    #pragma unroll
    for (int s = 0; s < 8; ++s) o1 += part_l[(s * AIB + row) * 33 + d] * wf_l[s * AIB + row];
    float o2 = 0.f;
    #pragma unroll
    for (int r = 0; r < R_; ++r) o2 += prb[row * 41 + r] * rve[r * 32 + d];
    float val = (o1 + o2) / lrow_l[row];
    ob[(long)(ib0 + row) * D_ + h * 32 + d] = f2b(val);
  }
}

extern "C" void kernel_launch(void* const* d_in, const int* in_sizes, int n_in,
                              void* d_out, int out_size, void* d_ws, size_t ws_size,
                              hipStream_t stream){
  const float* x    = (const float*)d_in[0];
  const int*   rel  = (const int*)d_in[1];
  const float* Wq   = (const float*)d_in[2];
  const float* bq   = (const float*)d_in[3];
  const float* Wk   = (const float*)d_in[4];
  const float* bk   = (const float*)d_in[5];
  const float* Wv   = (const float*)d_in[6];
  const float* bv   = (const float*)d_in[7];
  const float* Wo   = (const float*)d_in[8];
  const float* bo   = (const float*)d_in[9];
  const float* rke  = (const float*)d_in[10];
  const float* rve  = (const float*)d_in[11];
  const float* W1   = (const float*)d_in[12];
  const float* b1   = (const float*)d_in[13];
  const float* W2   = (const float*)d_in[14];
  const float* b2   = (const float*)d_in[15];
  const float* ln1g = (const float*)d_in[16];
  const float* ln1b = (const float*)d_in[17];
  const float* ln2g = (const float*)d_in[18];
  const float* ln2b = (const float*)d_in[19];
  const float* lnfg = (const float*)d_in[20];
  const float* lnfb = (const float*)d_in[21];

  char* wsb = (char*)d_ws;
  size_t off = 0;
  auto alloc = [&](size_t bytes){ void* p = wsb + off; off += (bytes + 255) & ~255ull; return p; };
  float*  xw   = (float*) alloc((size_t)N_ * D_ * 4);
  ushort* qkvb = (ushort*)alloc((size_t)3 * H_ * N_ * DK_ * 2);
  ushort* vbt  = (ushort*)alloc((size_t)H_ * DK_ * N_ * 2);
  ushort* xnb  = (ushort*)alloc((size_t)N_ * D_ * 2);
  ushort* obf  = (ushort*)alloc((size_t)N_ * D_ * 2);
  ushort* hidb = (ushort*)alloc((size_t)N_ * FF_ * 2);
  uint*   rel8 = (uint*)  alloc((size_t)N_ * N_);
  ushort* wqT  = (ushort*)alloc((size_t)L_ * D_ * D_ * 2);
  ushort* wkT  = (ushort*)alloc((size_t)L_ * D_ * D_ * 2);
  ushort* wvT  = (ushort*)alloc((size_t)L_ * D_ * D_ * 2);
  ushort* woT  = (ushort*)alloc((size_t)L_ * D_ * D_ * 2);
  ushort* w1T  = (ushort*)alloc((size_t)L_ * D_ * FF_ * 2);
  ushort* w2T  = (ushort*)alloc((size_t)L_ * D_ * FF_ * 2);
  (void)ws_size; (void)in_sizes; (void)n_in; (void)out_size;

  ushort* qb = qkvb;
  ushort* kb = qkvb + (size_t)H_ * N_ * DK_;

  dim3 tb(32, 8);
  wcast_kernel<<<dim3(D_/32,  D_/32,  L_), tb, 0, stream>>>(Wq, wqT, D_, D_);
  wcast_kernel<<<dim3(D_/32,  D_/32,  L_), tb, 0, stream>>>(Wk, wkT, D_, D_);
  wcast_kernel<<<dim3(D_/32,  D_/32,  L_), tb, 0, stream>>>(Wv, wvT, D_, D_);
  wcast_kernel<<<dim3(D_/32,  D_/32,  L_), tb, 0, stream>>>(Wo, woT, D_, D_);
  wcast_kernel<<<dim3(FF_/32, D_/32,  L_), tb, 0, stream>>>(W1, w1T, D_, FF_);
  wcast_kernel<<<dim3(D_/32,  FF_/32, L_), tb, 0, stream>>>(W2, w2T, FF_, D_);
  rel8_kernel<<<N_ * N_ / 1024, 256, 0, stream>>>(rel, rel8);

  hipMemcpyAsync(xw, x, (size_t)N_ * D_ * 4, hipMemcpyDeviceToDevice, stream);

  for (int l = 0; l < L_; ++l){
    ln_kernel<1><<<N_, 64, 0, stream>>>(xw, ln1g + l * D_, ln1b + l * D_, xnb, nullptr);
    gemm_kernel<1,0,0,0,1><<<dim3(768/64, N_/64), 256, 0, stream>>>(
        xnb, wqT + (size_t)l * D_ * D_, wkT + (size_t)l * D_ * D_, wvT + (size_t)l * D_ * D_,
        bq + l * D_, bk + l * D_, bv + l * D_,
        nullptr, nullptr, qkvb, vbt, N_, 768, D_);
    attn_kernel<<<dim3(N_/AIB, H_), 512, 0, stream>>>(
        qb, kb, vbt, rke + (size_t)l * R_ * DK_, rve + (size_t)l * R_ * DK_,
        (const unsigned char*)rel8, obf);
    gemm_kernel<0,0,1,1,0><<<dim3(D_/64, N_/64), 256, 0, stream>>>(
        obf, woT + (size_t)l * D_ * D_, nullptr, nullptr,
        bo + l * D_, nullptr, nullptr,
        xw, xw, nullptr, nullptr, N_, D_, D_);
    ln_kernel<1><<<N_, 64, 0, stream>>>(xw, ln2g + l * D_, ln2b + l * D_, xnb, nullptr);
    gemm_kernel<0,1,0,0,1><<<dim3(FF_/64, N_/64), 256, 0, stream>>>(
        xnb, w1T + (size_t)l * D_ * FF_, nullptr, nullptr,
        b1 + l * FF_, nullptr, nullptr,
        nullptr, nullptr, hidb, nullptr, N_, FF_, D_);
    gemm_kernel<0,0,1,1,0><<<dim3(D_/64, N_/64), 256, 0, stream>>>(
        hidb, w2T + (size_t)l * FF_ * D_, nullptr, nullptr,
        b2 + l * D_, nullptr, nullptr,
        xw, xw, nullptr, nullptr, N_, D_, FF_);
  }
  ln_kernel<0><<<N_, 64, 0, stream>>>(xw, lnfg, lnfb, nullptr, (float*)d_out);
}